// Round 1
// baseline (654.689 us; speedup 1.0000x reference)
//
#include <hip/hip_runtime.h>
#include <stdint.h>

#define N_ENT 100000
#define D1    200
#define BATCH 1024
#define KPAD  224            // 200 padded to 7*32
#define NPAD  100096         // 782*128
#define NTILES 782

typedef unsigned short ushort_t;
typedef __attribute__((ext_vector_type(8))) short short8;
typedef __attribute__((ext_vector_type(4))) float f32x4;

__constant__ int c_perm[11] = {8, 0, 3, 9, 4, 5, 6, 7, 1, 10, 2};

__device__ __forceinline__ unsigned short f2bf(float f) {
    unsigned int u = __float_as_uint(f);
    unsigned int r = (u + 0x7fffu + ((u >> 16) & 1u)) >> 16;
    return (unsigned short)r;
}

__device__ __forceinline__ int sym_idx(int a, int b) {
    int i = a < b ? a : b;
    int j = a < b ? b : a;
    return i * D1 - (i * (i - 1)) / 2 + (j - i);
}
// requires i < j
__device__ __forceinline__ int asym_idx(int i, int j) {
    return i * D1 - (i * (i + 1)) / 2 + (j - i - 1);
}

// ---------------- E fp32 -> bf16 padded (NPAD x KPAD), 8 elems/thread ----------------
__global__ void conv_E(const float* __restrict__ E, ushort_t* __restrict__ Epad) {
    int idx = blockIdx.x * 256 + threadIdx.x;          // one per 8 ushorts
    if (idx >= NPAD * KPAD / 8) return;
    int n = idx / (KPAD / 8);                          // 28 chunks per row
    int k0 = (idx - n * (KPAD / 8)) * 8;
    short8 o;
    if (n < N_ENT && k0 < D1) {                        // D1 % 8 == 0, no straddle
        const float* src = E + n * D1 + k0;
        f32x4 v0 = *(const f32x4*)src;
        f32x4 v1 = *(const f32x4*)(src + 4);
        o[0] = (short)f2bf(v0[0]); o[1] = (short)f2bf(v0[1]);
        o[2] = (short)f2bf(v0[2]); o[3] = (short)f2bf(v0[3]);
        o[4] = (short)f2bf(v1[0]); o[5] = (short)f2bf(v1[1]);
        o[6] = (short)f2bf(v1[2]); o[7] = (short)f2bf(v1[3]);
    } else {
        o = (short8){0, 0, 0, 0, 0, 0, 0, 0};
    }
    *(short8*)&Epad[idx * 8] = o;
}

// ---------------- M[rel] = sum_i R[rel,i] * W[i] (11 x 200 x 200) ----------------
__global__ void build_M(const float* __restrict__ R1, const float* __restrict__ R2,
                        const float* __restrict__ R3, const float* __restrict__ W1,
                        const float* __restrict__ W2, const float* __restrict__ W3,
                        float* __restrict__ M) {
    int rel = blockIdx.y;
    int e = blockIdx.x * 256 + threadIdx.x;
    if (e >= D1 * D1) return;
    int j = e / D1;
    int k = e - j * D1;
    float acc = 0.f;
    if (rel < 3) {
        int si = sym_idx(j, k);
        #pragma unroll 6
        for (int i = 0; i < 30; i++) acc += R1[rel * 30 + i] * W1[i * 20100 + si];
    } else if (rel < 8) {
        if (j != k) {
            int ai = (j < k) ? asym_idx(j, k) : asym_idx(k, j);
            float s = (j < k) ? 1.f : -1.f;
            #pragma unroll 6
            for (int i = 0; i < 30; i++) acc += R2[(rel - 3) * 30 + i] * s * W2[i * 19900 + ai];
        }
    } else {
        const float* r3 = R3 + (rel - 8) * 80;
        int si = sym_idx(j, k);
        #pragma unroll 6
        for (int i = 0; i < 30; i++) acc += r3[i] * W1[i * 20100 + si];
        if (j != k) {
            int ai = (j < k) ? asym_idx(j, k) : asym_idx(k, j);
            float s = (j < k) ? 1.f : -1.f;
            #pragma unroll 6
            for (int i = 0; i < 30; i++) acc += r3[30 + i] * s * W2[i * 19900 + ai];
        }
        #pragma unroll 5
        for (int i = 0; i < 20; i++) acc += r3[60 + i] * W3[i * 40000 + e];
    }
    M[rel * 40000 + e] = acc;
}

// ---------------- batchnorm stats over gathered E rows -> scale/shift ----------------
__global__ void bn0_stats(const float* __restrict__ E, const int* __restrict__ e1_idx,
                          const float* __restrict__ gamma, const float* __restrict__ beta,
                          float* __restrict__ scale, float* __restrict__ shift) {
    int f = blockIdx.x;
    int tid = threadIdx.x;
    float s = 0.f, sq = 0.f;
    for (int b = tid; b < BATCH; b += 256) {
        float v = E[e1_idx[b] * D1 + f];
        s += v; sq += v * v;
    }
    __shared__ float ls[256], lq[256];
    ls[tid] = s; lq[tid] = sq;
    __syncthreads();
    for (int off = 128; off > 0; off >>= 1) {
        if (tid < off) { ls[tid] += ls[tid + off]; lq[tid] += lq[tid + off]; }
        __syncthreads();
    }
    if (tid == 0) {
        float m = ls[0] * (1.f / BATCH);
        float var = lq[0] * (1.f / BATCH) - m * m;
        float rstd = rsqrtf(var + 1e-5f);
        scale[f] = rstd * gamma[f];
        shift[f] = beta[f] - m * rstd * gamma[f];
    }
}

__global__ void bn1_stats(const float* __restrict__ y,
                          const float* __restrict__ gamma, const float* __restrict__ beta,
                          float* __restrict__ scale, float* __restrict__ shift) {
    int f = blockIdx.x;
    int tid = threadIdx.x;
    float s = 0.f, sq = 0.f;
    for (int b = tid; b < BATCH; b += 256) {
        float v = y[b * D1 + f];
        s += v; sq += v * v;
    }
    __shared__ float ls[256], lq[256];
    ls[tid] = s; lq[tid] = sq;
    __syncthreads();
    for (int off = 128; off > 0; off >>= 1) {
        if (tid < off) { ls[tid] += ls[tid + off]; lq[tid] += lq[tid + off]; }
        __syncthreads();
    }
    if (tid == 0) {
        float m = ls[0] * (1.f / BATCH);
        float var = lq[0] * (1.f / BATCH) - m * m;
        float rstd = rsqrtf(var + 1e-5f);
        scale[f] = rstd * gamma[f];
        shift[f] = beta[f] - m * rstd * gamma[f];
    }
}

// ---------------- y[b,k] = sum_j bn0(E[e1[b]])[j] * M[rel_b][j][k] ----------------
__global__ void xw_kernel(const float* __restrict__ E, const int* __restrict__ e1_idx,
                          const int* __restrict__ r_idx,
                          const float* __restrict__ scale0, const float* __restrict__ shift0,
                          const float* __restrict__ M, float* __restrict__ y) {
    int b = blockIdx.x;
    int tid = threadIdx.x;
    __shared__ float xs[D1];
    __shared__ int s_rel;
    if (tid == 0) s_rel = c_perm[r_idx[b]];
    int e1 = e1_idx[b];
    if (tid < D1) xs[tid] = E[e1 * D1 + tid] * scale0[tid] + shift0[tid];
    __syncthreads();
    if (tid < D1) {
        const float* Mr = M + s_rel * 40000;
        float acc = 0.f;
        #pragma unroll 8
        for (int j = 0; j < D1; j++) acc += xs[j] * Mr[j * D1 + tid];
        y[b * D1 + tid] = acc;
    }
}

// ---------------- x2 bf16 padded (BATCH x KPAD), 8 elems/thread ----------------
__global__ void x2pad_kernel(const float* __restrict__ y,
                             const float* __restrict__ scale1, const float* __restrict__ shift1,
                             ushort_t* __restrict__ x2) {
    int idx = blockIdx.x * 256 + threadIdx.x;
    if (idx >= BATCH * KPAD / 8) return;
    int b = idx / (KPAD / 8);
    int k0 = (idx - b * (KPAD / 8)) * 8;
    short8 o;
    if (k0 < D1) {
        const float* src = y + b * D1 + k0;
        f32x4 v0 = *(const f32x4*)src;
        f32x4 v1 = *(const f32x4*)(src + 4);
        #pragma unroll
        for (int j = 0; j < 4; j++) {
            o[j]     = (short)f2bf(v0[j] * scale1[k0 + j]     + shift1[k0 + j]);
            o[j + 4] = (short)f2bf(v1[j] * scale1[k0 + j + 4] + shift1[k0 + j + 4]);
        }
    } else {
        o = (short8){0, 0, 0, 0, 0, 0, 0, 0};
    }
    *(short8*)&x2[idx * 8] = o;
}

// ---------------- scores GEMM: out[b,n] = sigmoid(sum_k x2[b,k]*Epad[n,k]) ----------------
__device__ __forceinline__ void gld_lds16(const void* g, void* l) {
    __builtin_amdgcn_global_load_lds(
        (const __attribute__((address_space(1))) unsigned int*)(uintptr_t)g,
        (__attribute__((address_space(3))) unsigned int*)(unsigned int)(uintptr_t)l,
        16, 0, 0);
}

// Double-buffered, 1-deep prefetch with counted vmcnt (T3+T4 minimal 2-phase).
// Grid: (m-tiles, n-tiles) so the 8 blocks sharing a B-tile are dispatch-adjacent.
__global__ __launch_bounds__(256) void gemm_score(const ushort_t* __restrict__ x2,
                                                  const ushort_t* __restrict__ Epad,
                                                  float* __restrict__ out) {
    __shared__ ushort_t As[2][128 * 32];
    __shared__ ushort_t Bs[2][128 * 32];
    const int tid = threadIdx.x;
    const int wave = tid >> 6;
    const int lane = tid & 63;
    const int wm = wave >> 1, wn = wave & 1;
    const int quad = lane >> 4, l16 = lane & 15;
    const int tile_m = blockIdx.x * 128;   // 8 m-tiles (fast-varying)
    const int tile_n = blockIdx.y * 128;   // 782 n-tiles

    const int srow = tid >> 2;   // 0..63
    const int sseg = tid & 3;    // 0..3

    const ushort_t* gA = x2 + (tile_m + srow) * KPAD + sseg * 8;
    const ushort_t* gB = Epad + (size_t)(tile_n + srow) * KPAD + sseg * 8;

    f32x4 acc[4][4];
    #pragma unroll
    for (int i = 0; i < 4; i++)
        #pragma unroll
        for (int j = 0; j < 4; j++) acc[i][j] = (f32x4){0.f, 0.f, 0.f, 0.f};

    // stage tile (K-offset kb) into buffer c: 4 gld_lds per thread (2 A rounds + 2 B rounds)
#define STAGE(c, kb) do {                                                     \
        gld_lds16(gA + (kb),              &As[c][wave * 512]);                \
        gld_lds16(gA + 64 * KPAD + (kb),  &As[c][2048 + wave * 512]);         \
        gld_lds16(gB + (kb),              &Bs[c][wave * 512]);                \
        gld_lds16(gB + 64 * KPAD + (kb),  &Bs[c][2048 + wave * 512]);         \
    } while (0)

    STAGE(0, 0);

    #pragma unroll
    for (int t = 0; t < KPAD / 32; ++t) {
        const int cur = t & 1;
        if (t < KPAD / 32 - 1) {
            STAGE(cur ^ 1, (t + 1) * 32);                 // prefetch next tile
            asm volatile("s_waitcnt vmcnt(4)" ::: "memory");  // wait: tile t landed, t+1 in flight
        } else {
            asm volatile("s_waitcnt vmcnt(0)" ::: "memory");  // tail: drain
        }
        __builtin_amdgcn_s_barrier();
        __builtin_amdgcn_sched_barrier(0);                // pin: no hoisting of ds_reads above

        short8 a_frag[4], b_frag[4];
        #pragma unroll
        for (int f = 0; f < 4; f++) {
            a_frag[f] = *(const short8*)&As[cur][(wm * 64 + f * 16 + l16) * 32 + quad * 8];
            b_frag[f] = *(const short8*)&Bs[cur][(wn * 64 + f * 16 + l16) * 32 + quad * 8];
        }
        #pragma unroll
        for (int fm = 0; fm < 4; fm++)
            #pragma unroll
            for (int fn = 0; fn < 4; fn++)
                acc[fm][fn] = __builtin_amdgcn_mfma_f32_16x16x32_bf16(
                    a_frag[fm], b_frag[fn], acc[fm][fn], 0, 0, 0);

        __builtin_amdgcn_s_barrier();                     // all waves done reading buf[cur]
        __builtin_amdgcn_sched_barrier(0);                // pin: next STAGE can't hoist above
    }
#undef STAGE

    // epilogue: D layout col = lane&15, row = quad*4 + reg
    #pragma unroll
    for (int fm = 0; fm < 4; fm++) {
        int m = tile_m + wm * 64 + fm * 16 + quad * 4;
        #pragma unroll
        for (int fn = 0; fn < 4; fn++) {
            int n = tile_n + wn * 64 + fn * 16 + l16;
            if (n < N_ENT) {
                float* po = out + (size_t)m * N_ENT + n;
                #pragma unroll
                for (int r = 0; r < 4; r++) {
                    float v = acc[fm][fn][r];
                    po[(size_t)r * N_ENT] = 1.f / (1.f + __expf(-v));
                }
            }
        }
    }
}

extern "C" void kernel_launch(void* const* d_in, const int* in_sizes, int n_in,
                              void* d_out, int out_size, void* d_ws, size_t ws_size,
                              hipStream_t stream) {
    const float* E  = (const float*)d_in[0];
    const float* R1 = (const float*)d_in[1];
    const float* R2 = (const float*)d_in[2];
    const float* R3 = (const float*)d_in[3];
    const float* W1 = (const float*)d_in[4];
    const float* W2 = (const float*)d_in[5];
    const float* W3 = (const float*)d_in[6];
    const float* g0 = (const float*)d_in[7];
    const float* b0 = (const float*)d_in[8];
    const float* g1 = (const float*)d_in[9];
    const float* b1 = (const float*)d_in[10];
    const int* e1_idx = (const int*)d_in[11];
    const int* r_idx  = (const int*)d_in[12];
    float* out = (float*)d_out;

    char* ws = (char*)d_ws;
    ushort_t* Epad = (ushort_t*)ws;                       // NPAD*KPAD*2 = 44,843,008 B
    float* M       = (float*)(ws + 44843008);             // 11*40000*4 = 1,760,000 B
    float* scale0  = (float*)(ws + 46603008);
    float* shift0  = scale0 + D1;
    float* scale1  = shift0 + D1;
    float* shift1  = scale1 + D1;
    float* y       = shift1 + D1;                         // BATCH*D1*4 = 819,200 B
    ushort_t* x2   = (ushort_t*)(y + BATCH * D1);         // BATCH*KPAD*2 = 458,752 B

    conv_E<<<(NPAD * KPAD / 8 + 255) / 256, 256, 0, stream>>>(E, Epad);
    build_M<<<dim3((D1 * D1 + 255) / 256, 11), 256, 0, stream>>>(R1, R2, R3, W1, W2, W3, M);
    bn0_stats<<<D1, 256, 0, stream>>>(E, e1_idx, g0, b0, scale0, shift0);
    xw_kernel<<<BATCH, 256, 0, stream>>>(E, e1_idx, r_idx, scale0, shift0, M, y);
    bn1_stats<<<D1, 256, 0, stream>>>(y, g1, b1, scale1, shift1);
    x2pad_kernel<<<(BATCH * KPAD / 8 + 255) / 256, 256, 0, stream>>>(y, scale1, shift1, x2);
    gemm_score<<<dim3(BATCH / 128, NTILES), 256, 0, stream>>>(x2, Epad, out);
}

// Round 2
// 618.021 us; speedup vs baseline: 1.0593x; 1.0593x over previous
//
#include <hip/hip_runtime.h>
#include <stdint.h>

#define N_ENT 100000
#define D1    200
#define BATCH 1024
#define KPAD  224            // 200 padded to 7*32
#define NPAD  100096         // 782*128
#define NTILES 782

typedef unsigned short ushort_t;
typedef __attribute__((ext_vector_type(8))) short short8;
typedef __attribute__((ext_vector_type(4))) float f32x4;

__constant__ int c_perm[11] = {8, 0, 3, 9, 4, 5, 6, 7, 1, 10, 2};

__device__ __forceinline__ unsigned short f2bf(float f) {
    unsigned int u = __float_as_uint(f);
    unsigned int r = (u + 0x7fffu + ((u >> 16) & 1u)) >> 16;
    return (unsigned short)r;
}

__device__ __forceinline__ int sym_idx(int a, int b) {
    int i = a < b ? a : b;
    int j = a < b ? b : a;
    return i * D1 - (i * (i - 1)) / 2 + (j - i);
}
// requires i < j
__device__ __forceinline__ int asym_idx(int i, int j) {
    return i * D1 - (i * (i + 1)) / 2 + (j - i - 1);
}

// ---------------- E fp32 -> bf16 padded (NPAD x KPAD), 8 elems/thread ----------------
__global__ void conv_E(const float* __restrict__ E, ushort_t* __restrict__ Epad) {
    int idx = blockIdx.x * 256 + threadIdx.x;          // one per 8 ushorts
    if (idx >= NPAD * KPAD / 8) return;
    int n = idx / (KPAD / 8);                          // 28 chunks per row
    int k0 = (idx - n * (KPAD / 8)) * 8;
    short8 o;
    if (n < N_ENT && k0 < D1) {                        // D1 % 8 == 0, no straddle
        const float* src = E + n * D1 + k0;
        f32x4 v0 = *(const f32x4*)src;
        f32x4 v1 = *(const f32x4*)(src + 4);
        o[0] = (short)f2bf(v0[0]); o[1] = (short)f2bf(v0[1]);
        o[2] = (short)f2bf(v0[2]); o[3] = (short)f2bf(v0[3]);
        o[4] = (short)f2bf(v1[0]); o[5] = (short)f2bf(v1[1]);
        o[6] = (short)f2bf(v1[2]); o[7] = (short)f2bf(v1[3]);
    } else {
        o = (short8){0, 0, 0, 0, 0, 0, 0, 0};
    }
    *(short8*)&Epad[idx * 8] = o;
}

// ---------------- M[rel] = sum_i R[rel,i] * W[i] (11 x 200 x 200) ----------------
__global__ void build_M(const float* __restrict__ R1, const float* __restrict__ R2,
                        const float* __restrict__ R3, const float* __restrict__ W1,
                        const float* __restrict__ W2, const float* __restrict__ W3,
                        float* __restrict__ M) {
    int rel = blockIdx.y;
    int e = blockIdx.x * 256 + threadIdx.x;
    if (e >= D1 * D1) return;
    int j = e / D1;
    int k = e - j * D1;
    float acc = 0.f;
    if (rel < 3) {
        int si = sym_idx(j, k);
        #pragma unroll 6
        for (int i = 0; i < 30; i++) acc += R1[rel * 30 + i] * W1[i * 20100 + si];
    } else if (rel < 8) {
        if (j != k) {
            int ai = (j < k) ? asym_idx(j, k) : asym_idx(k, j);
            float s = (j < k) ? 1.f : -1.f;
            #pragma unroll 6
            for (int i = 0; i < 30; i++) acc += R2[(rel - 3) * 30 + i] * s * W2[i * 19900 + ai];
        }
    } else {
        const float* r3 = R3 + (rel - 8) * 80;
        int si = sym_idx(j, k);
        #pragma unroll 6
        for (int i = 0; i < 30; i++) acc += r3[i] * W1[i * 20100 + si];
        if (j != k) {
            int ai = (j < k) ? asym_idx(j, k) : asym_idx(k, j);
            float s = (j < k) ? 1.f : -1.f;
            #pragma unroll 6
            for (int i = 0; i < 30; i++) acc += r3[30 + i] * s * W2[i * 19900 + ai];
        }
        #pragma unroll 5
        for (int i = 0; i < 20; i++) acc += r3[60 + i] * W3[i * 40000 + e];
    }
    M[rel * 40000 + e] = acc;
}

// ---------------- batchnorm stats over gathered E rows -> scale/shift ----------------
__global__ void bn0_stats(const float* __restrict__ E, const int* __restrict__ e1_idx,
                          const float* __restrict__ gamma, const float* __restrict__ beta,
                          float* __restrict__ scale, float* __restrict__ shift) {
    int f = blockIdx.x;
    int tid = threadIdx.x;
    float s = 0.f, sq = 0.f;
    for (int b = tid; b < BATCH; b += 256) {
        float v = E[e1_idx[b] * D1 + f];
        s += v; sq += v * v;
    }
    __shared__ float ls[256], lq[256];
    ls[tid] = s; lq[tid] = sq;
    __syncthreads();
    for (int off = 128; off > 0; off >>= 1) {
        if (tid < off) { ls[tid] += ls[tid + off]; lq[tid] += lq[tid + off]; }
        __syncthreads();
    }
    if (tid == 0) {
        float m = ls[0] * (1.f / BATCH);
        float var = lq[0] * (1.f / BATCH) - m * m;
        float rstd = rsqrtf(var + 1e-5f);
        scale[f] = rstd * gamma[f];
        shift[f] = beta[f] - m * rstd * gamma[f];
    }
}

__global__ void bn1_stats(const float* __restrict__ y,
                          const float* __restrict__ gamma, const float* __restrict__ beta,
                          float* __restrict__ scale, float* __restrict__ shift) {
    int f = blockIdx.x;
    int tid = threadIdx.x;
    float s = 0.f, sq = 0.f;
    for (int b = tid; b < BATCH; b += 256) {
        float v = y[b * D1 + f];
        s += v; sq += v * v;
    }
    __shared__ float ls[256], lq[256];
    ls[tid] = s; lq[tid] = sq;
    __syncthreads();
    for (int off = 128; off > 0; off >>= 1) {
        if (tid < off) { ls[tid] += ls[tid + off]; lq[tid] += lq[tid + off]; }
        __syncthreads();
    }
    if (tid == 0) {
        float m = ls[0] * (1.f / BATCH);
        float var = lq[0] * (1.f / BATCH) - m * m;
        float rstd = rsqrtf(var + 1e-5f);
        scale[f] = rstd * gamma[f];
        shift[f] = beta[f] - m * rstd * gamma[f];
    }
}

// ---------------- y[b,k] = sum_j bn0(E[e1[b]])[j] * M[rel_b][j][k] ----------------
__global__ void xw_kernel(const float* __restrict__ E, const int* __restrict__ e1_idx,
                          const int* __restrict__ r_idx,
                          const float* __restrict__ scale0, const float* __restrict__ shift0,
                          const float* __restrict__ M, float* __restrict__ y) {
    int b = blockIdx.x;
    int tid = threadIdx.x;
    __shared__ float xs[D1];
    __shared__ int s_rel;
    if (tid == 0) s_rel = c_perm[r_idx[b]];
    int e1 = e1_idx[b];
    if (tid < D1) xs[tid] = E[e1 * D1 + tid] * scale0[tid] + shift0[tid];
    __syncthreads();
    if (tid < D1) {
        const float* Mr = M + s_rel * 40000;
        float acc = 0.f;
        #pragma unroll 8
        for (int j = 0; j < D1; j++) acc += xs[j] * Mr[j * D1 + tid];
        y[b * D1 + tid] = acc;
    }
}

// ---------------- x2 bf16 padded (BATCH x KPAD), 8 elems/thread ----------------
__global__ void x2pad_kernel(const float* __restrict__ y,
                             const float* __restrict__ scale1, const float* __restrict__ shift1,
                             ushort_t* __restrict__ x2) {
    int idx = blockIdx.x * 256 + threadIdx.x;
    if (idx >= BATCH * KPAD / 8) return;
    int b = idx / (KPAD / 8);
    int k0 = (idx - b * (KPAD / 8)) * 8;
    short8 o;
    if (k0 < D1) {
        const float* src = y + b * D1 + k0;
        f32x4 v0 = *(const f32x4*)src;
        f32x4 v1 = *(const f32x4*)(src + 4);
        #pragma unroll
        for (int j = 0; j < 4; j++) {
            o[j]     = (short)f2bf(v0[j] * scale1[k0 + j]     + shift1[k0 + j]);
            o[j + 4] = (short)f2bf(v1[j] * scale1[k0 + j + 4] + shift1[k0 + j + 4]);
        }
    } else {
        o = (short8){0, 0, 0, 0, 0, 0, 0, 0};
    }
    *(short8*)&x2[idx * 8] = o;
}

// ---------------- scores GEMM: out[b,n] = sigmoid(sum_k x2[b,k]*Epad[n,k]) ----------------
__device__ __forceinline__ void gld_lds16(const void* g, void* l) {
    __builtin_amdgcn_global_load_lds(
        (const __attribute__((address_space(1))) unsigned int*)(uintptr_t)g,
        (__attribute__((address_space(3))) unsigned int*)(unsigned int)(uintptr_t)l,
        16, 0, 0);
}

// T3 "minimum 2-phase" recipe (m248v2): STAGE(next) -> ds_read(cur) -> MFMA ->
// vmcnt(0) -> s_barrier.  ONE barrier per K-step; no sched_barrier; no counted vmcnt.
// Safety: compiler-inserted lgkmcnt before MFMA retires each wave's ds_reads of
// buf[cur] before it reaches the barrier; between barriers all waves write only
// buf[cur^1] -> no LDS read/write overlap.
__global__ __launch_bounds__(256) void gemm_score(const ushort_t* __restrict__ x2,
                                                  const ushort_t* __restrict__ Epad,
                                                  float* __restrict__ out) {
    __shared__ ushort_t As[2][128 * 32];
    __shared__ ushort_t Bs[2][128 * 32];
    const int tid = threadIdx.x;
    const int wave = tid >> 6;
    const int lane = tid & 63;
    const int wm = wave >> 1, wn = wave & 1;
    const int quad = lane >> 4, l16 = lane & 15;
    const int tile_n = blockIdx.x * 128;   // round-0 mapping
    const int tile_m = blockIdx.y * 128;

    const int srow = tid >> 2;   // 0..63
    const int sseg = tid & 3;    // 0..3

    const ushort_t* gA = x2 + (tile_m + srow) * KPAD + sseg * 8;
    const ushort_t* gB = Epad + (size_t)(tile_n + srow) * KPAD + sseg * 8;

    f32x4 acc[4][4];
    #pragma unroll
    for (int i = 0; i < 4; i++)
        #pragma unroll
        for (int j = 0; j < 4; j++) acc[i][j] = (f32x4){0.f, 0.f, 0.f, 0.f};

#define STAGE(c, kb) do {                                                     \
        gld_lds16(gA + (kb),              &As[c][wave * 512]);                \
        gld_lds16(gA + 64 * KPAD + (kb),  &As[c][2048 + wave * 512]);         \
        gld_lds16(gB + (kb),              &Bs[c][wave * 512]);                \
        gld_lds16(gB + 64 * KPAD + (kb),  &Bs[c][2048 + wave * 512]);         \
    } while (0)

    // prologue: stage tile 0, drain, barrier
    STAGE(0, 0);
    asm volatile("s_waitcnt vmcnt(0)" ::: "memory");
    __builtin_amdgcn_s_barrier();

    #pragma unroll
    for (int t = 0; t < KPAD / 32; ++t) {
        const int cur = t & 1;
        if (t < KPAD / 32 - 1)
            STAGE(cur ^ 1, (t + 1) * 32);   // issue next tile; lands during compute

        short8 a_frag[4], b_frag[4];
        #pragma unroll
        for (int f = 0; f < 4; f++) {
            a_frag[f] = *(const short8*)&As[cur][(wm * 64 + f * 16 + l16) * 32 + quad * 8];
            b_frag[f] = *(const short8*)&Bs[cur][(wn * 64 + f * 16 + l16) * 32 + quad * 8];
        }
        #pragma unroll
        for (int fm = 0; fm < 4; fm++)
            #pragma unroll
            for (int fn = 0; fn < 4; fn++)
                acc[fm][fn] = __builtin_amdgcn_mfma_f32_16x16x32_bf16(
                    a_frag[fm], b_frag[fn], acc[fm][fn], 0, 0, 0);

        asm volatile("s_waitcnt vmcnt(0)" ::: "memory");  // next tile landed (had whole compute to fly)
        __builtin_amdgcn_s_barrier();
    }
#undef STAGE

    // epilogue: D layout col = lane&15, row = quad*4 + reg
    #pragma unroll
    for (int fm = 0; fm < 4; fm++) {
        int m = tile_m + wm * 64 + fm * 16 + quad * 4;
        #pragma unroll
        for (int fn = 0; fn < 4; fn++) {
            int n = tile_n + wn * 64 + fn * 16 + l16;
            if (n < N_ENT) {
                float* po = out + (size_t)m * N_ENT + n;
                #pragma unroll
                for (int r = 0; r < 4; r++) {
                    float v = acc[fm][fn][r];
                    po[(size_t)r * N_ENT] = 1.f / (1.f + __expf(-v));
                }
            }
        }
    }
}

extern "C" void kernel_launch(void* const* d_in, const int* in_sizes, int n_in,
                              void* d_out, int out_size, void* d_ws, size_t ws_size,
                              hipStream_t stream) {
    const float* E  = (const float*)d_in[0];
    const float* R1 = (const float*)d_in[1];
    const float* R2 = (const float*)d_in[2];
    const float* R3 = (const float*)d_in[3];
    const float* W1 = (const float*)d_in[4];
    const float* W2 = (const float*)d_in[5];
    const float* W3 = (const float*)d_in[6];
    const float* g0 = (const float*)d_in[7];
    const float* b0 = (const float*)d_in[8];
    const float* g1 = (const float*)d_in[9];
    const float* b1 = (const float*)d_in[10];
    const int* e1_idx = (const int*)d_in[11];
    const int* r_idx  = (const int*)d_in[12];
    float* out = (float*)d_out;

    char* ws = (char*)d_ws;
    ushort_t* Epad = (ushort_t*)ws;                       // NPAD*KPAD*2 = 44,843,008 B
    float* M       = (float*)(ws + 44843008);             // 11*40000*4 = 1,760,000 B
    float* scale0  = (float*)(ws + 46603008);
    float* shift0  = scale0 + D1;
    float* scale1  = shift0 + D1;
    float* shift1  = scale1 + D1;
    float* y       = shift1 + D1;                         // BATCH*D1*4 = 819,200 B
    ushort_t* x2   = (ushort_t*)(y + BATCH * D1);         // BATCH*KPAD*2 = 458,752 B

    conv_E<<<(NPAD * KPAD / 8 + 255) / 256, 256, 0, stream>>>(E, Epad);
    build_M<<<dim3((D1 * D1 + 255) / 256, 11), 256, 0, stream>>>(R1, R2, R3, W1, W2, W3, M);
    bn0_stats<<<D1, 256, 0, stream>>>(E, e1_idx, g0, b0, scale0, shift0);
    xw_kernel<<<BATCH, 256, 0, stream>>>(E, e1_idx, r_idx, scale0, shift0, M, y);
    bn1_stats<<<D1, 256, 0, stream>>>(y, g1, b1, scale1, shift1);
    x2pad_kernel<<<(BATCH * KPAD / 8 + 255) / 256, 256, 0, stream>>>(y, scale1, shift1, x2);
    gemm_score<<<dim3(NTILES, BATCH / 128), 256, 0, stream>>>(x2, Epad, out);
}